// Round 1
// baseline (190.265 us; speedup 1.0000x reference)
//
#include <hip/hip_runtime.h>
#include <cmath>

namespace {

constexpr int kDim = 5;
constexpr int kWidth = 64;
constexpr int kSave = 64;
constexpr int kTraj = 16;      // trajectories per block
constexpr int kThreads = 256;
constexpr int kMaxSteps = 64;
constexpr int LDW = 68;        // padded stride for width-64 rows (bank spread, 16B aligned)
constexpr int LDD = 8;         // padded stride for dim-5 rows

__device__ __forceinline__ float softplusf(float x) {
  // jax.nn.softplus(x) = max(x,0) + log1p(exp(-|x|))
  return fmaxf(x, 0.0f) + log1pf(expf(-fabsf(x)));
}

__global__ __launch_bounds__(kThreads)
void node_tsit5_kernel(const float* __restrict__ gy0,
                       const float* __restrict__ gte,
                       const float* __restrict__ gW1, const float* __restrict__ gb1,
                       const float* __restrict__ gW2, const float* __restrict__ gb2,
                       const float* __restrict__ gW3, const float* __restrict__ gb3,
                       const float* __restrict__ gW4, const float* __restrict__ gb4,
                       float* __restrict__ out) {
  // Tsit5 coefficients, rounded to f32 exactly as JAX weak-type promotion does
  const float A21 = 0.161f;
  const float A31 = -0.008480655492356989f, A32 = 0.335480655492357f;
  const float A41 = 2.8971530571054935f, A42 = -6.359448489975075f, A43 = 4.3622954328695815f;
  const float A51 = 5.325864828439257f, A52 = -11.748883564062828f, A53 = 7.4955393428898365f,
              A54 = -0.09249506636175525f;
  const float A61 = 5.86145544294642f, A62 = -12.92096931784711f, A63 = 8.159367898576159f,
              A64 = -0.071584973281401f, A65 = -0.028269050394068383f;
  const float B1 = 0.09646076681806523f, B2 = 0.01f, B3 = 0.4798896504144996f,
              B4 = 1.379008574103742f, B5 = -3.290069515436081f, B6 = 2.324710524099774f;
  const float E1 = -0.00178001105222577714f, E2 = -0.0008164344596567469f,
              E3 = 0.007880878010261995f, E4 = -0.1447110071732629f, E5 = 0.5823571654525552f,
              E6 = -0.45808210592918697f, E7 = 0.015151515151515152f;

  __shared__ float sW1[kWidth * LDD];
  __shared__ float sW2[kWidth * LDW];
  __shared__ float sW3[kWidth * LDW];
  __shared__ float sW4[kDim * LDW];
  __shared__ float sB1[kWidth], sB2[kWidth], sB3[kWidth];
  __shared__ float sB4[kDim];
  __shared__ float sTe[kSave];
  __shared__ float hA[kTraj * LDW];
  __shared__ float hB[kTraj * LDW];
  __shared__ float sy[kTraj * LDD];
  __shared__ float syn[kTraj * LDD];
  __shared__ float sz[kTraj * LDD];
  __shared__ float sesq[kTraj * LDD];
  __shared__ float sk[7][kTraj * LDD];
  __shared__ float s_t[kTraj], s_h[kTraj], s_hc[kTraj], s_tn[kTraj], s_hn[kTraj];
  __shared__ int s_ok[kTraj], s_done[kTraj];
  __shared__ int s_alldone;

  const int tid = threadIdx.x;
  const int bid = blockIdx.x;
  const int tt = tid & 15;   // trajectory within block
  const int gg = tid >> 4;   // neuron group (4 neurons per thread)

  // ---- stage weights / inputs into LDS ----
  for (int idx = tid; idx < kWidth * kWidth; idx += kThreads) {
    int j = idx >> 6, i = idx & 63;
    sW2[j * LDW + i] = gW2[idx];
    sW3[j * LDW + i] = gW3[idx];
  }
  for (int idx = tid; idx < kWidth * kDim; idx += kThreads) {
    int j = idx / kDim, d = idx - j * kDim;
    sW1[j * LDD + d] = gW1[idx];
  }
  for (int idx = tid; idx < kDim * kWidth; idx += kThreads) {
    int d = idx >> 6, i = idx & 63;
    sW4[d * LDW + i] = gW4[idx];
  }
  if (tid < kWidth) { sB1[tid] = gb1[tid]; sB2[tid] = gb2[tid]; sB3[tid] = gb3[tid]; }
  if (tid < kDim) sB4[tid] = gb4[tid];
  if (tid < kSave) sTe[tid] = gte[tid];
  if (tid < kTraj * kDim) {
    int t = tid & 15, d = tid >> 4;
    sy[t * LDD + d] = gy0[(bid * kTraj + t) * kDim + d];
  }
  if (tid < kTraj) { s_t[tid] = gte[0]; s_h[tid] = 0.1f; }
  // zero this block's output slice (d_out is poisoned 0xAA before every launch)
  {
    float* ob = out + (size_t)bid * kTraj * kSave * kDim;
    for (int idx = tid; idx < kTraj * kSave * kDim; idx += kThreads) ob[idx] = 0.0f;
  }
  __syncthreads();

  const float t0v = sTe[0];
  const float t1v = sTe[kSave - 1];

  // saves at/before t0 get y0
  if (tid < kTraj * kDim) {
    int t = tid & 15, d = tid >> 4;
    float yv = sy[t * LDD + d];
    for (int n = 0; n < kSave; ++n)
      if (sTe[n] <= t0v + 1e-6f)
        out[((size_t)(bid * kTraj + t) * kSave + n) * kDim + d] = yv;
  }

  // dst = MLP(src); src/dst are [kTraj][LDD]; uniformly executed by all threads
  auto evalF = [&](const float* src, float* dst) {
    // layer 1: 5 -> 64
    {
      float zv[kDim];
      #pragma unroll
      for (int d = 0; d < kDim; ++d) zv[d] = src[tt * LDD + d];
      #pragma unroll
      for (int c = 0; c < 4; ++c) {
        int j = 4 * gg + c;
        float acc = sB1[j];
        #pragma unroll
        for (int d = 0; d < kDim; ++d) acc = fmaf(sW1[j * LDD + d], zv[d], acc);
        hA[tt * LDW + j] = softplusf(acc);
      }
    }
    __syncthreads();
    // layer 2: 64 -> 64 (hA -> hB)
    {
      int j0 = 4 * gg;
      float a0 = sB2[j0 + 0], a1 = sB2[j0 + 1], a2 = sB2[j0 + 2], a3 = sB2[j0 + 3];
      const float* ar = &hA[tt * LDW];
      const float* w0 = &sW2[(j0 + 0) * LDW];
      const float* w1 = &sW2[(j0 + 1) * LDW];
      const float* w2 = &sW2[(j0 + 2) * LDW];
      const float* w3 = &sW2[(j0 + 3) * LDW];
      #pragma unroll
      for (int i = 0; i < kWidth; i += 4) {
        float4 a = *(const float4*)(ar + i);
        float4 q0 = *(const float4*)(w0 + i);
        float4 q1 = *(const float4*)(w1 + i);
        float4 q2 = *(const float4*)(w2 + i);
        float4 q3 = *(const float4*)(w3 + i);
        a0 = fmaf(a.w, q0.w, fmaf(a.z, q0.z, fmaf(a.y, q0.y, fmaf(a.x, q0.x, a0))));
        a1 = fmaf(a.w, q1.w, fmaf(a.z, q1.z, fmaf(a.y, q1.y, fmaf(a.x, q1.x, a1))));
        a2 = fmaf(a.w, q2.w, fmaf(a.z, q2.z, fmaf(a.y, q2.y, fmaf(a.x, q2.x, a2))));
        a3 = fmaf(a.w, q3.w, fmaf(a.z, q3.z, fmaf(a.y, q3.y, fmaf(a.x, q3.x, a3))));
      }
      float4 r;
      r.x = softplusf(a0); r.y = softplusf(a1); r.z = softplusf(a2); r.w = softplusf(a3);
      *(float4*)&hB[tt * LDW + j0] = r;
    }
    __syncthreads();
    // layer 3: 64 -> 64 (hB -> hA)
    {
      int j0 = 4 * gg;
      float a0 = sB3[j0 + 0], a1 = sB3[j0 + 1], a2 = sB3[j0 + 2], a3 = sB3[j0 + 3];
      const float* ar = &hB[tt * LDW];
      const float* w0 = &sW3[(j0 + 0) * LDW];
      const float* w1 = &sW3[(j0 + 1) * LDW];
      const float* w2 = &sW3[(j0 + 2) * LDW];
      const float* w3 = &sW3[(j0 + 3) * LDW];
      #pragma unroll
      for (int i = 0; i < kWidth; i += 4) {
        float4 a = *(const float4*)(ar + i);
        float4 q0 = *(const float4*)(w0 + i);
        float4 q1 = *(const float4*)(w1 + i);
        float4 q2 = *(const float4*)(w2 + i);
        float4 q3 = *(const float4*)(w3 + i);
        a0 = fmaf(a.w, q0.w, fmaf(a.z, q0.z, fmaf(a.y, q0.y, fmaf(a.x, q0.x, a0))));
        a1 = fmaf(a.w, q1.w, fmaf(a.z, q1.z, fmaf(a.y, q1.y, fmaf(a.x, q1.x, a1))));
        a2 = fmaf(a.w, q2.w, fmaf(a.z, q2.z, fmaf(a.y, q2.y, fmaf(a.x, q2.x, a2))));
        a3 = fmaf(a.w, q3.w, fmaf(a.z, q3.z, fmaf(a.y, q3.y, fmaf(a.x, q3.x, a3))));
      }
      float4 r;
      r.x = softplusf(a0); r.y = softplusf(a1); r.z = softplusf(a2); r.w = softplusf(a3);
      *(float4*)&hA[tt * LDW + j0] = r;
    }
    __syncthreads();
    // layer 4: 64 -> 5 (no activation)
    if (tid < kTraj * kDim) {
      int t = tid & 15, d = tid >> 4;
      float acc = sB4[d];
      const float* ar = &hA[t * LDW];
      const float* wr = &sW4[d * LDW];
      #pragma unroll
      for (int i = 0; i < kWidth; i += 4) {
        float4 a = *(const float4*)(ar + i);
        float4 w = *(const float4*)(wr + i);
        acc = fmaf(a.w, w.w, fmaf(a.z, w.z, fmaf(a.y, w.y, fmaf(a.x, w.x, acc))));
      }
      dst[t * LDD + d] = acc;
    }
    __syncthreads();
  };

  // k1 = f(y0); thereafter FSAL: k1 <- (accepted ? k7 : k1) is bitwise identical
  evalF(sy, sk[0]);

  for (int step = 0; step < kMaxSteps; ++step) {
    if (tid < kTraj) {
      float tc = s_t[tid];
      int dn = tc >= t1v - 1e-6f;
      s_done[tid] = dn;
      s_hc[tid] = dn ? 0.0f : fminf(s_h[tid], t1v - tc);
    }
    __syncthreads();
    if (tid == 0) {
      int ad = 1;
      for (int i = 0; i < kTraj; ++i) ad &= s_done[i];
      s_alldone = ad;
    }
    __syncthreads();
    if (s_alldone) break;   // uniform: all remaining iterations are no-ops

    const bool l80 = tid < kTraj * kDim;
    const int ut = tid & 15, ud = tid >> 4;
    const int uo = ut * LDD + ud;
    float hcv = 0.f;
    if (l80) hcv = s_hc[ut];

    if (l80) sz[uo] = fmaf(hcv, A21 * sk[0][uo], sy[uo]);
    __syncthreads();
    evalF(sz, sk[1]);

    if (l80) sz[uo] = fmaf(hcv, fmaf(A32, sk[1][uo], A31 * sk[0][uo]), sy[uo]);
    __syncthreads();
    evalF(sz, sk[2]);

    if (l80) sz[uo] = fmaf(hcv, fmaf(A43, sk[2][uo], fmaf(A42, sk[1][uo], A41 * sk[0][uo])), sy[uo]);
    __syncthreads();
    evalF(sz, sk[3]);

    if (l80) sz[uo] = fmaf(hcv, fmaf(A54, sk[3][uo], fmaf(A53, sk[2][uo],
                       fmaf(A52, sk[1][uo], A51 * sk[0][uo]))), sy[uo]);
    __syncthreads();
    evalF(sz, sk[4]);

    if (l80) sz[uo] = fmaf(hcv, fmaf(A65, sk[4][uo], fmaf(A64, sk[3][uo], fmaf(A63, sk[2][uo],
                       fmaf(A62, sk[1][uo], A61 * sk[0][uo])))), sy[uo]);
    __syncthreads();
    evalF(sz, sk[5]);

    if (l80) syn[uo] = fmaf(hcv, fmaf(B6, sk[5][uo], fmaf(B5, sk[4][uo], fmaf(B4, sk[3][uo],
                        fmaf(B3, sk[2][uo], fmaf(B2, sk[1][uo], B1 * sk[0][uo]))))), sy[uo]);
    __syncthreads();
    evalF(syn, sk[6]);   // k7 (FSAL)

    if (l80) {
      float err = hcv * fmaf(E7, sk[6][uo], fmaf(E6, sk[5][uo], fmaf(E5, sk[4][uo],
                  fmaf(E4, sk[3][uo], fmaf(E3, sk[2][uo], fmaf(E2, sk[1][uo], E1 * sk[0][uo]))))));
      float sc = fmaf(1e-3f, fmaxf(fabsf(sy[uo]), fabsf(syn[uo])), 1e-6f);
      float r = err / sc;
      sesq[uo] = r * r;
    }
    __syncthreads();
    if (tid < kTraj) {
      float s = 0.f;
      #pragma unroll
      for (int d = 0; d < kDim; ++d) s += sesq[tid * LDD + d];
      float enorm = sqrtf(s / 5.0f);
      float enc = fmaxf(enorm, 1e-10f);
      int accept = enorm <= 1.0f;
      float factor = fminf(fmaxf(0.9f * powf(enc, -0.2f), 0.2f), 10.0f);
      int dn = s_done[tid];
      int ok = accept && !dn;
      float hcc = s_hc[tid];
      s_tn[tid] = ok ? s_t[tid] + hcc : s_t[tid];
      s_hn[tid] = dn ? s_h[tid] : hcc * factor;
      s_ok[tid] = ok;
    }
    __syncthreads();
    // cubic Hermite interpolation for save points in (t, t_next]
    if (s_ok[tt]) {
      float tOld = s_t[tt], hcs = s_hc[tt], tNew = s_tn[tt];
      float inv = 1.0f / fmaxf(hcs, 1e-12f);
      float yv[kDim], ynv[kDim], k1v[kDim], k7v[kDim];
      #pragma unroll
      for (int d = 0; d < kDim; ++d) {
        yv[d]  = sy[tt * LDD + d];
        ynv[d] = syn[tt * LDD + d];
        k1v[d] = hcs * sk[0][tt * LDD + d];
        k7v[d] = hcs * sk[6][tt * LDD + d];
      }
      #pragma unroll
      for (int q = 0; q < 4; ++q) {
        int n = 4 * gg + q;
        float te = sTe[n];
        if (te > tOld && te <= tNew + 1e-6f) {
          float sx = (te - tOld) * inv;
          float s2 = sx * sx, s3 = s2 * sx;
          float h00 = 2.f * s3 - 3.f * s2 + 1.f;
          float h10 = s3 - 2.f * s2 + sx;
          float h01 = -2.f * s3 + 3.f * s2;
          float h11 = s3 - s2;
          float* op = out + ((size_t)(bid * kTraj + tt) * kSave + n) * kDim;
          #pragma unroll
          for (int d = 0; d < kDim; ++d)
            op[d] = h00 * yv[d] + h10 * k1v[d] + h01 * ynv[d] + h11 * k7v[d];
        }
      }
    }
    __syncthreads();
    // state update (after interpolation has consumed old state)
    if (l80 && s_ok[ut]) { sy[uo] = syn[uo]; sk[0][uo] = sk[6][uo]; }
    if (tid < kTraj) { s_t[tid] = s_tn[tid]; s_h[tid] = s_hn[tid]; }
    __syncthreads();
  }
}

}  // namespace

extern "C" void kernel_launch(void* const* d_in, const int* in_sizes, int n_in,
                              void* d_out, int out_size, void* d_ws, size_t ws_size,
                              hipStream_t stream) {
  const float* y0 = (const float*)d_in[0];
  const float* te = (const float*)d_in[1];
  const float* W1 = (const float*)d_in[2];
  const float* b1 = (const float*)d_in[3];
  const float* W2 = (const float*)d_in[4];
  const float* b2 = (const float*)d_in[5];
  const float* W3 = (const float*)d_in[6];
  const float* b3 = (const float*)d_in[7];
  const float* W4 = (const float*)d_in[8];
  const float* b4 = (const float*)d_in[9];
  float* out = (float*)d_out;

  const int batch = in_sizes[0] / kDim;      // 4096
  const int blocks = batch / kTraj;          // 256
  hipLaunchKernelGGL(node_tsit5_kernel, dim3(blocks), dim3(kThreads), 0, stream,
                     y0, te, W1, b1, W2, b2, W3, b3, W4, b4, out);
}